// Round 6
// baseline (357.302 us; speedup 1.0000x reference)
//
#include <hip/hip_runtime.h>
#include <hip/hip_bf16.h>
#include <hip/hip_fp16.h>

#define BATCH   4
#define NNODES  10000
#define NEDGES  160000
#define FDIM    128
#define FEDIM   16
#define LNEPS   1e-3f
#define NTOTE   (BATCH * NEDGES)
#define NTOTN   (BATCH * NNODES)

typedef __attribute__((ext_vector_type(8))) short v8s;   // 8 bf16 (4 VGPRs)
typedef __attribute__((ext_vector_type(4))) float v4f;   // 4 fp32 acc

// workspace layout
#define AGG_BYTES   ((size_t)NTOTN * FDIM * 2)            // 10.24 MB fp16 aggregate
#define CNT_OFF     AGG_BYTES                             // int[40000][4] sub-histograms (640KB)
#define CNT_BYTES   ((size_t)NTOTN * 4 * 4)
#define CUR_OFF     (CNT_OFF + CNT_BYTES)                 // int[40000][4] scan output / scatter cursor
#define P_OFF       (CUR_OFF + CNT_BYTES)                 // bf16 [B*N][256]: [P1|P2], rows PERMUTED [c*8+nt]
#define P_BYTES     ((size_t)NTOTN * 256 * 2)             // 20.48 MB
#define WTCAT_OFF   (P_OFF + P_BYTES)                     // bf16 [256][128] transposed [W1|W2]
#define WTUPD_OFF   (WTCAT_OFF + (size_t)256 * 128 * 2)   // bf16 [128][256] transposed W_upd
#define W3T_OFF     (WTUPD_OFF + (size_t)128 * 256 * 2)   // bf16 [128][32] W3 transposed, K padded 16->32
#define REC_OFF     (W3T_OFF + (size_t)128 * 32 * 2)      // sorted 64B records = 40.96 MB
// record = 4 x uint4: [ ef bf16 x8 | ef bf16 x8 | {srcrow, dstrow, wgt, eid} | pad ]

static __device__ __forceinline__ unsigned short f2bf(float f) {
    __hip_bfloat16 h = __float2bfloat16(f);
    return *reinterpret_cast<unsigned short*>(&h);
}
static __device__ __forceinline__ float bfbits2f(unsigned bits16) {
    return __uint_as_float(bits16 << 16);
}

// GELU tanh-form rewritten as x*sigmoid(2z) with native rcp:
// g = x*e/(e+1) = x - x*rcp(e+1), e = exp(1.59576912*(x + 0.044715x^3))*... (2z)
// ~7 VALU inst vs ~20 (full-precision divide sequence). Algebraically identical; rcp ~1ulp.
static __device__ __forceinline__ float gelu_f(float x) {
    float x2 = x * x;
    float z2 = 1.5957691216f * x * __builtin_fmaf(0.044715f, x2, 1.0f);
    float e  = __expf(z2);
    float r  = __builtin_amdgcn_rcpf(e + 1.0f);
    return __builtin_fmaf(-x, r, x);
}

// dtype flag: gflag -> g_msg == ones. fp32 word0=0x3F800000 (low16==0); bf16 word0=0x3F803F80.
static __device__ __forceinline__ bool is_bf16_mode(const void* gflag) {
    return ((*reinterpret_cast<const unsigned*>(gflag)) & 0xFFFFu) != 0u;
}
static __device__ __forceinline__ float ld_f(const void* p, long i, bool bf) {
    return bf ? (float)reinterpret_cast<const __hip_bfloat16*>(p)[i]
              : reinterpret_cast<const float*>(p)[i];
}
static __device__ __forceinline__ uint4 pack8(const float* p) {
    float4 f0 = *reinterpret_cast<const float4*>(p);
    float4 f1 = *reinterpret_cast<const float4*>(p + 4);
    uint4 o;
    o.x = f2bf(f0.x) | ((unsigned)f2bf(f0.y) << 16);
    o.y = f2bf(f0.z) | ((unsigned)f2bf(f0.w) << 16);
    o.z = f2bf(f1.x) | ((unsigned)f2bf(f1.y) << 16);
    o.w = f2bf(f1.z) | ((unsigned)f2bf(f1.w) << 16);
    return o;
}
// 8 fp16 (uint4) -> 8 bf16 (uint4)
static __device__ __forceinline__ uint4 h8_to_bf8(uint4 u) {
    unsigned w[4] = {u.x, u.y, u.z, u.w};
    uint4 o; unsigned r[4];
    #pragma unroll
    for (int q = 0; q < 4; q++) {
        __half lo = *reinterpret_cast<const __half*>(&w[q]);
        unsigned short hib = (unsigned short)(w[q] >> 16);
        __half hi = *reinterpret_cast<const __half*>(&hib);
        r[q] = f2bf(__half2float(lo)) | ((unsigned)f2bf(__half2float(hi)) << 16);
    }
    o.x = r[0]; o.y = r[1]; o.z = r[2]; o.w = r[3];
    return o;
}

// ---- fused init: zero agg (640000 uint4) + zero counts4 + weight prep ----
#define NCAT (256 * 128)
#define NUPD (128 * 256)
#define NW3  (128 * 32)
__global__ __launch_bounds__(256) void init_kernel(
    const void* __restrict__ Wmsg, const void* __restrict__ Wupd,
    const void* __restrict__ gflag,
    unsigned short* __restrict__ WtCat,
    unsigned short* __restrict__ WtUpd,
    unsigned short* __restrict__ W3t,
    uint4* __restrict__ aggz,
    uint4* __restrict__ cntz) {
    bool bf = is_bf16_mode(gflag);
    int i = blockIdx.x * 256 + threadIdx.x;    // grid = 2500*256 = 640000 exactly
    aggz[i] = make_uint4(0, 0, 0, 0);
    if (i < (int)(CNT_BYTES / 16)) cntz[i] = make_uint4(0, 0, 0, 0);
    if (i < NCAT) {
        int n = i >> 7, k = i & 127;
        int src = (n < 128) ? (k * 128 + n) : ((128 + k) * 128 + (n - 128));
        WtCat[i] = bf ? reinterpret_cast<const unsigned short*>(Wmsg)[src]
                      : f2bf(reinterpret_cast<const float*>(Wmsg)[src]);
    } else if (i < NCAT + NUPD) {
        int j = i - NCAT;
        int n = j >> 8, c = j & 255;
        WtUpd[j] = bf ? reinterpret_cast<const unsigned short*>(Wupd)[c * 128 + n]
                      : f2bf(reinterpret_cast<const float*>(Wupd)[c * 128 + n]);
    } else if (i < NCAT + NUPD + NW3) {
        int j = i - NCAT - NUPD;
        int n = j >> 5, k = j & 31;
        W3t[j] = (k < 16) ? (bf ? reinterpret_cast<const unsigned short*>(Wmsg)[(256 + k) * 128 + n]
                                : f2bf(reinterpret_cast<const float*>(Wmsg)[(256 + k) * 128 + n]))
                          : (unsigned short)0;
    }
}

// single-block exclusive scan over 160000 sub-counts -> cursor4. Two-pass (re-read), no big arrays.
__global__ __launch_bounds__(1024) void scan_kernel(const int* __restrict__ counts4,
                                                    int* __restrict__ cursor4) {
    __shared__ int wsum[16];
    const int N4 = NTOTN * 4;              // 160000
    const int C = 160;                     // 1000 threads x 160
    int tid = threadIdx.x, lane = tid & 63, wave = tid >> 6;
    int lo = tid * C;
    const bool act = (lo < N4);
    int s = 0;
    if (act) {
        for (int q = 0; q < C / 4; q++) {
            int4 t4 = *reinterpret_cast<const int4*>(counts4 + lo + q * 4);
            s += t4.x + t4.y + t4.z + t4.w;
        }
    }
    int sc = s;
    #pragma unroll
    for (int off = 1; off < 64; off <<= 1) {
        int v = __shfl_up(sc, off);
        if (lane >= off) sc += v;
    }
    if (lane == 63) wsum[wave] = sc;
    __syncthreads();
    if (wave == 0 && lane < 16) {
        int t = wsum[lane];
        #pragma unroll
        for (int off = 1; off < 16; off <<= 1) {
            int v = __shfl_up(t, off);
            if (lane >= off) t += v;
        }
        wsum[lane] = t;
    }
    __syncthreads();
    int run = (wave > 0 ? wsum[wave - 1] : 0) + (sc - s);
    if (act) {
        for (int q = 0; q < C / 4; q++) {
            int4 t4 = *reinterpret_cast<const int4*>(counts4 + lo + q * 4);
            int4 o;
            o.x = run; run += t4.x;
            o.y = run; run += t4.y;
            o.z = run; run += t4.z;
            o.w = run; run += t4.w;
            *reinterpret_cast<int4*>(cursor4 + lo + q * 4) = o;
        }
    }
}

// scatter edges into dst-sorted 64B records via 4-way sub-cursors (4x less atomic contention)
__global__ __launch_bounds__(256) void sort_scatter(
    const int*  __restrict__ edges,
    const void* __restrict__ ew,
    const void* __restrict__ ed,
    const void* __restrict__ efeat,
    const void* __restrict__ gflag,
    int*        __restrict__ cursor4,
    uint4*      __restrict__ rec4)
{
    const bool bf = is_bf16_mode(gflag);
    int gid = blockIdx.x * 256 + threadIdx.x;   // grid exact: 2500*256 = NTOTE
    int b = gid / NEDGES;
    long be = gid;
    int2 e = reinterpret_cast<const int2*>(edges)[gid];
    float w = ld_f(ew, be, bf) * ld_f(ed, be * 2 + 1, bf);
    uint4 R0, R1;
    if (bf) {
        const unsigned short* ep = reinterpret_cast<const unsigned short*>(efeat) + be * FEDIM;
        R0 = *reinterpret_cast<const uint4*>(ep);
        R1 = *reinterpret_cast<const uint4*>(ep + 8);
    } else {
        const float* ep = reinterpret_cast<const float*>(efeat) + be * FEDIM;
        R0 = pack8(ep);
        R1 = pack8(ep + 8);
    }
    int pos = atomicAdd(&cursor4[((size_t)b * NNODES + e.y) * 4 + (threadIdx.x & 3)], 1);
    uint4* rp = rec4 + (size_t)pos * 4;
    rp[0] = R0;
    rp[1] = R1;
    rp[2] = make_uint4((unsigned)(b * NNODES + e.x),
                       (unsigned)(b * NNODES + e.y),
                       __float_as_uint(w), (unsigned)gid);
    rp[3] = make_uint4(0, 0, 0, 0);
}

// ---- precompute P = [nodes@W1 + b_msg | nodes@W2] (+ folded 4-way edge histogram) ----
__global__ __launch_bounds__(256) void pg_kernel(
    const void* __restrict__ nodes,
    const void* __restrict__ bmsg,
    const void* __restrict__ gflag,
    const unsigned short* __restrict__ Wt,    // [256][128]
    const int*  __restrict__ edges,
    int*        __restrict__ counts4,
    unsigned short*       __restrict__ P)     // [B*N][256] permuted
{
    const bool bf = is_bf16_mode(gflag);
    __shared__ unsigned short sW[128 * 40];
    __shared__ unsigned short sA[128 * 40];

    const int tid  = threadIdx.x;
    const int lane = tid & 63, wave = tid >> 6;
    const int c    = lane & 15, quad = lane >> 4;
    const int row0 = blockIdx.x * 128;
    const int half = blockIdx.y;
    const int NROWS = BATCH * NNODES;

    // folded histogram: y==0 blocks cover all edges, 8 strided per thread (pre-barrier)
    if (half == 0) {
        #pragma unroll
        for (int k = 0; k < 8; k++) {
            int g = blockIdx.x * 2048 + k * 256 + tid;
            if (g < NTOTE) {
                int2 e = reinterpret_cast<const int2*>(edges)[g];
                atomicAdd(&counts4[((size_t)(g / NEDGES) * NNODES + e.y) * 4 + (tid & 3)], 1);
            }
        }
    }

    float bcol[8];
    #pragma unroll
    for (int nt = 0; nt < 8; nt++)
        bcol[nt] = (half == 0) ? ld_f(bmsg, nt * 16 + c, bf) : 0.f;

    v4f acc[2][8];
    #pragma unroll
    for (int mt = 0; mt < 2; mt++)
        #pragma unroll
        for (int nt = 0; nt < 8; nt++) { v4f z = {0.f, 0.f, 0.f, 0.f}; acc[mt][nt] = z; }

    for (int ks = 0; ks < 4; ks++) {
        #pragma unroll
        for (int q = tid; q < 512; q += 256) {
            int n = q >> 2, part = q & 3;
            *reinterpret_cast<uint4*>(&sW[n * 40 + part * 8]) =
                *reinterpret_cast<const uint4*>(Wt + (half * 128 + n) * 128 + ks * 32 + part * 8);
        }
        #pragma unroll
        for (int q = tid; q < 512; q += 256) {
            int t = q >> 2, part = q & 3;
            int row = row0 + t; if (row >= NROWS) row = NROWS - 1;
            long off = (size_t)row * FDIM + ks * 32 + part * 8;
            uint4 v = bf ? *reinterpret_cast<const uint4*>(reinterpret_cast<const unsigned short*>(nodes) + off)
                         : pack8(reinterpret_cast<const float*>(nodes) + off);
            *reinterpret_cast<uint4*>(&sA[t * 40 + part * 8]) = v;
        }
        __syncthreads();

        v8s a0 = *reinterpret_cast<const v8s*>(&sA[(wave * 32 + c) * 40 + quad * 8]);
        v8s a1 = *reinterpret_cast<const v8s*>(&sA[(wave * 32 + 16 + c) * 40 + quad * 8]);
        #pragma unroll
        for (int nt = 0; nt < 8; nt++) {
            v8s bfr = *reinterpret_cast<const v8s*>(&sW[(nt * 16 + c) * 40 + quad * 8]);
            acc[0][nt] = __builtin_amdgcn_mfma_f32_16x16x32_bf16(a0, bfr, acc[0][nt], 0, 0, 0);
            acc[1][nt] = __builtin_amdgcn_mfma_f32_16x16x32_bf16(a1, bfr, acc[1][nt], 0, 0, 0);
        }
        __syncthreads();
    }

    #pragma unroll
    for (int mt = 0; mt < 2; mt++)
        #pragma unroll
        for (int r = 0; r < 4; r++) {
            int row = row0 + wave * 32 + mt * 16 + quad * 4 + r;
            if (row < NROWS) {
                float v[8];
                #pragma unroll
                for (int nt = 0; nt < 8; nt++) v[nt] = acc[mt][nt][r] + bcol[nt];
                uint4 o;
                o.x = f2bf(v[0]) | ((unsigned)f2bf(v[1]) << 16);
                o.y = f2bf(v[2]) | ((unsigned)f2bf(v[3]) << 16);
                o.z = f2bf(v[4]) | ((unsigned)f2bf(v[5]) << 16);
                o.w = f2bf(v[6]) | ((unsigned)f2bf(v[7]) << 16);
                *reinterpret_cast<uint4*>(P + (size_t)row * 256 + half * 128 + c * 8) = o;
            }
        }
}

// ---- per-edge (dst-SORTED, 64B recs): each quad owns 32 CONTIGUOUS sorted edges (4 groups
// of the proven 8-edge MFMA/postprocess phase). Runs wholly inside the chunk -> ONE PLAIN
// fp16x2 STORE (complete sum, no other writer); chunk-straddling runs -> fp16x2 atomics.
__global__ __launch_bounds__(256) void edge_kernel(
    const unsigned short* __restrict__ P,     // [B*N][256] bf16, permuted rows
    const uint4*          __restrict__ rec4,  // 64B records
    const unsigned short* __restrict__ W3t,   // [128][32] bf16, K-padded
    const void* __restrict__ gmsg,            // gamma (and dtype flag)
    const void* __restrict__ betamsg,
    __half*     __restrict__ agg)             // [B*N][128] fp16
{
    const bool bf = is_bf16_mode(gmsg);
    const int tid  = threadIdx.x;
    const int lane = tid & 63, wave = tid >> 6;
    const int c    = lane & 15, quad = lane >> 4;
    const int wbase = blockIdx.x * 512 + wave * 128;  // wave's 128 sorted edges
    const int q0    = wbase + quad * 32;              // this quad's 32 sorted edges

    float gcol[8], becol[8];
    #pragma unroll
    for (int nt = 0; nt < 8; nt++) {
        gcol[nt]  = ld_f(gmsg, nt * 16 + c, bf);
        becol[nt] = ld_f(betamsg, nt * 16 + c, bf);
    }

    v8s bfrag[8];
    #pragma unroll
    for (int nt = 0; nt < 8; nt++)
        bfrag[nt] = *reinterpret_cast<const v8s*>(W3t + (nt * 16 + c) * 32 + quad * 8);

    // neighbor-chunk dst headers for straddle detection (quad-uniform loads)
    const int prevd = (q0 == 0) ? -1 : (int)rec4[(size_t)(q0 - 1) * 4 + 2].y;
    const int nextd = (q0 + 32 >= NTOTE) ? -1 : (int)rec4[(size_t)(q0 + 32) * 4 + 2].y;

    const bool even = !(c & 1);
    float racc[8];
    int  cur = -1;
    bool owned = true;   // current run started inside this chunk

    auto flushv = [&](int dstrow, bool plain) {
        __half* aout = agg + (size_t)dstrow * FDIM;
        #pragma unroll
        for (int np = 0; np < 4; np++) {
            int nt = np * 2;
            float t0 = __shfl_xor(racc[nt], 1);       // partner is in-quad, same branch path
            float t1 = __shfl_xor(racc[nt + 1], 1);
            __half2 v = even ? __floats2half2_rn(racc[nt], t0)
                             : __floats2half2_rn(t1, racc[nt + 1]);
            int hoff = even ? (nt * 16 + c) : ((nt + 1) * 16 + c - 1);
            if (plain) *reinterpret_cast<__half2*>(aout + hoff) = v;
            else       unsafeAtomicAdd(reinterpret_cast<__half2*>(aout + hoff), v);
        }
    };

    for (int g = 0; g < 4; g++) {
        v4f acc[2][8];
        #pragma unroll
        for (int mt = 0; mt < 2; mt++)
            #pragma unroll
            for (int nt = 0; nt < 8; nt++) { v4f z = {0.f, 0.f, 0.f, 0.f}; acc[mt][nt] = z; }

        // MFMA Q for this group: A-row c = edge (c>>2)*32 + g*8 + mt*4 + (c&3) of the wave
        #pragma unroll
        for (int mt = 0; mt < 2; mt++) {
            v8s a = {0, 0, 0, 0, 0, 0, 0, 0};
            if (quad < 2) {
                int slot = wbase + (c >> 2) * 32 + g * 8 + mt * 4 + (c & 3);
                uint4 u = rec4[(size_t)slot * 4 + quad];
                a = *reinterpret_cast<v8s*>(&u);
            }
            #pragma unroll
            for (int nt = 0; nt < 8; nt++)
                acc[mt][nt] = __builtin_amdgcn_mfma_f32_16x16x32_bf16(a, bfrag[nt], acc[mt][nt], 0, 0, 0);
        }

        #pragma unroll
        for (int mt = 0; mt < 2; mt++) {
            uint4 H[4];
            #pragma unroll
            for (int r = 0; r < 4; r++)
                H[r] = rec4[(size_t)(q0 + g * 8 + mt * 4 + r) * 4 + 2];
            uint4 U1[4], U2[4];
            #pragma unroll
            for (int r = 0; r < 4; r++) {
                U1[r] = *reinterpret_cast<const uint4*>(P + (size_t)H[r].x * 256 + c * 8);
                U2[r] = *reinterpret_cast<const uint4*>(P + (size_t)H[r].y * 256 + 128 + c * 8);
            }
            #pragma unroll
            for (int r = 0; r < 4; r++) {
                unsigned w1[4] = {U1[r].x, U1[r].y, U1[r].z, U1[r].w};
                unsigned w2[4] = {U2[r].x, U2[r].y, U2[r].z, U2[r].w};
                float h[8];
                #pragma unroll
                for (int q = 0; q < 4; q++) {
                    h[q * 2]     = bfbits2f(w1[q] & 0xFFFFu) + bfbits2f(w2[q] & 0xFFFFu) + acc[mt][q * 2][r];
                    h[q * 2 + 1] = __uint_as_float(w1[q] & 0xFFFF0000u) + __uint_as_float(w2[q] & 0xFFFF0000u)
                                   + acc[mt][q * 2 + 1][r];
                }
                float s = 0.f, sq = 0.f;
                #pragma unroll
                for (int nt = 0; nt < 8; nt++) {
                    float gg = gelu_f(h[nt]);
                    h[nt] = gg; s += gg; sq += gg * gg;
                }
                #pragma unroll
                for (int off = 1; off < 16; off <<= 1) {   // stays inside the quad
                    s  += __shfl_xor(s, off);
                    sq += __shfl_xor(sq, off);
                }
                float mu  = s * (1.0f / 128.0f);
                float var = sq * (1.0f / 128.0f) - mu * mu;
                float rs  = __builtin_amdgcn_rsqf(var + LNEPS);
                float wgt = __uint_as_float(H[r].z);
                int d = (int)H[r].y;
                if (d != cur) {               // quad-uniform branch
                    if (cur >= 0) { flushv(cur, owned); owned = true; }
                    else owned = (d != prevd);   // first run: extends left?
                    cur = d;
                    #pragma unroll
                    for (int nt = 0; nt < 8; nt++)
                        racc[nt] = ((h[nt] - mu) * rs * gcol[nt] + becol[nt]) * wgt;
                } else {
                    #pragma unroll
                    for (int nt = 0; nt < 8; nt++)
                        racc[nt] += ((h[nt] - mu) * rs * gcol[nt] + becol[nt]) * wgt;
                }
            }
        }
    }
    flushv(cur, owned && (cur != nextd));   // last run: plain iff starts AND ends inside
}

// ---- node update: [nodes | agg(fp16)] @ W_upd + b -> GELU -> LN -> out ----
__global__ __launch_bounds__(256) void upd_kernel(
    const void* __restrict__ nodes,
    const __half* __restrict__ agg,          // [B*N][128] fp16
    const unsigned short* __restrict__ Wt,   // [128][256]
    const void* __restrict__ bupd,
    const void* __restrict__ gupd,
    const void* __restrict__ beupd,
    void*       __restrict__ out)
{
    const bool bf = is_bf16_mode(gupd);
    __shared__ unsigned short sW[128 * 40];
    __shared__ unsigned short sA[64 * 40];

    const int tid  = threadIdx.x;
    const int lane = tid & 63, wave = tid >> 6;
    const int c    = lane & 15, quad = lane >> 4;
    const int row0 = blockIdx.x * 64;

    float bcol[8], gcol[8], becol[8];
    #pragma unroll
    for (int nt = 0; nt < 8; nt++) {
        int col = nt * 16 + c;
        bcol[nt]  = ld_f(bupd, col, bf);
        gcol[nt]  = ld_f(gupd, col, bf);
        becol[nt] = ld_f(beupd, col, bf);
    }

    v4f acc[8];
    #pragma unroll
    for (int nt = 0; nt < 8; nt++) { v4f z = {0.f, 0.f, 0.f, 0.f}; acc[nt] = z; }

    for (int ks = 0; ks < 8; ks++) {
        #pragma unroll
        for (int q = tid; q < 512; q += 256) {
            int n = q >> 2, part = q & 3;
            *reinterpret_cast<uint4*>(&sW[n * 40 + part * 8]) =
                *reinterpret_cast<const uint4*>(Wt + n * 256 + ks * 32 + part * 8);
        }
        {
            int t = tid >> 2, part = tid & 3;
            int row = row0 + t;
            uint4 v;
            if (ks < 4) {
                long off = (size_t)row * FDIM + ks * 32 + part * 8;
                v = bf ? *reinterpret_cast<const uint4*>(reinterpret_cast<const unsigned short*>(nodes) + off)
                       : pack8(reinterpret_cast<const float*>(nodes) + off);
            } else {
                uint4 u = *reinterpret_cast<const uint4*>(
                    reinterpret_cast<const unsigned short*>(agg) + (size_t)row * FDIM + (ks - 4) * 32 + part * 8);
                v = h8_to_bf8(u);
            }
            *reinterpret_cast<uint4*>(&sA[t * 40 + part * 8]) = v;
        }
        __syncthreads();

        v8s a0 = *reinterpret_cast<const v8s*>(&sA[(wave * 16 + c) * 40 + quad * 8]);
        #pragma unroll
        for (int nt = 0; nt < 8; nt++) {
            v8s bfr = *reinterpret_cast<const v8s*>(&sW[(nt * 16 + c) * 40 + quad * 8]);
            acc[nt] = __builtin_amdgcn_mfma_f32_16x16x32_bf16(a0, bfr, acc[nt], 0, 0, 0);
        }
        __syncthreads();
    }

    float s[4] = {0, 0, 0, 0}, sq[4] = {0, 0, 0, 0};
    #pragma unroll
    for (int nt = 0; nt < 8; nt++) {
        v4f v = acc[nt];
        #pragma unroll
        for (int r = 0; r < 4; r++) {
            float g = gelu_f(v[r] + bcol[nt]);
            v[r] = g;
            s[r] += g; sq[r] += g * g;
        }
        acc[nt] = v;
    }
    #pragma unroll
    for (int off = 1; off < 16; off <<= 1) {
        #pragma unroll
        for (int r = 0; r < 4; r++) {
            s[r]  += __shfl_xor(s[r], off);
            sq[r] += __shfl_xor(sq[r], off);
        }
    }
    #pragma unroll
    for (int r = 0; r < 4; r++) {
        float mu  = s[r] * (1.0f / 128.0f);
        float var = sq[r] * (1.0f / 128.0f) - mu * mu;
        float rs  = __builtin_amdgcn_rsqf(var + LNEPS);
        int row = row0 + wave * 16 + quad * 4 + r;
        #pragma unroll
        for (int nt = 0; nt < 8; nt++) {
            float y = (acc[nt][r] - mu) * rs * gcol[nt] + becol[nt];
            size_t oi = (size_t)row * FDIM + nt * 16 + c;
            if (bf) reinterpret_cast<__hip_bfloat16*>(out)[oi] = __float2bfloat16(y);
            else    reinterpret_cast<float*>(out)[oi] = y;
        }
    }
}

extern "C" void kernel_launch(void* const* d_in, const int* in_sizes, int n_in,
                              void* d_out, int out_size, void* d_ws, size_t ws_size,
                              hipStream_t stream)
{
    const void* nodes   = d_in[0];
    const void* efeat   = d_in[1];
    const int*  edges   = (const int*)d_in[2];
    const void* ew      = d_in[3];
    const void* ed      = d_in[4];
    const void* Wmsg    = d_in[5];
    const void* bmsg    = d_in[6];
    const void* gmsg    = d_in[7];   // ones -> dtype flag
    const void* betamsg = d_in[8];
    const void* Wupd    = d_in[9];
    const void* bupd    = d_in[10];
    const void* gupd    = d_in[11];
    const void* betaupd = d_in[12];

    char* ws = (char*)d_ws;
    __half* agg          = (__half*)ws;
    int*    counts4      = (int*)(ws + CNT_OFF);
    int*    cursor4      = (int*)(ws + CUR_OFF);
    unsigned short* P    = (unsigned short*)(ws + P_OFF);
    unsigned short* WtCat= (unsigned short*)(ws + WTCAT_OFF);
    unsigned short* WtUpd= (unsigned short*)(ws + WTUPD_OFF);
    unsigned short* W3t  = (unsigned short*)(ws + W3T_OFF);
    uint4*          rec4 = (uint4*)(ws + REC_OFF);

    // 6 dispatches: init(+zero agg/counts4+prep), pg(+hist), scan, scatter, edge, upd
    init_kernel<<<2500, 256, 0, stream>>>(
        Wmsg, Wupd, gmsg, WtCat, WtUpd, W3t, (uint4*)agg, (uint4*)counts4);
    pg_kernel<<<dim3(313, 2), 256, 0, stream>>>(
        nodes, bmsg, gmsg, WtCat, edges, counts4, P);
    scan_kernel<<<1, 1024, 0, stream>>>(counts4, cursor4);
    sort_scatter<<<NTOTE / 256, 256, 0, stream>>>(
        edges, ew, ed, efeat, gmsg, cursor4, rec4);
    edge_kernel<<<NTOTE / 512, 256, 0, stream>>>(
        P, rec4, W3t, gmsg, betamsg, agg);
    upd_kernel<<<NTOTN / 64, 256, 0, stream>>>(
        nodes, agg, WtUpd, bupd, gupd, betaupd, d_out);
}

// Round 7
// 301.385 us; speedup vs baseline: 1.1855x; 1.1855x over previous
//
#include <hip/hip_runtime.h>
#include <hip/hip_bf16.h>
#include <hip/hip_fp16.h>

#define BATCH   4
#define NNODES  10000
#define NEDGES  160000
#define FDIM    128
#define FEDIM   16
#define LNEPS   1e-3f
#define NTOTE   (BATCH * NEDGES)
#define NTOTN   (BATCH * NNODES)

typedef __attribute__((ext_vector_type(8))) short v8s;   // 8 bf16 (4 VGPRs)
typedef __attribute__((ext_vector_type(4))) float v4f;   // 4 fp32 acc

// workspace layout
#define AGG_BYTES   ((size_t)NTOTN * FDIM * 2)            // 10.24 MB fp16 aggregate
#define CNT_OFF     AGG_BYTES                             // int[40000] histogram
#define CNT_BYTES   ((size_t)NTOTN * 4)
#define CUR_OFF     (CNT_OFF + CNT_BYTES)                 // int[40000] scan output / scatter cursor
#define P_OFF       (CUR_OFF + CNT_BYTES)                 // bf16 [B*N][256]: [P1|P2], rows PERMUTED [c*8+nt]
#define P_BYTES     ((size_t)NTOTN * 256 * 2)             // 20.48 MB
#define WTCAT_OFF   (P_OFF + P_BYTES)                     // bf16 [256][128] transposed [W1|W2]
#define WTUPD_OFF   (WTCAT_OFF + (size_t)256 * 128 * 2)   // bf16 [128][256] transposed W_upd
#define W3T_OFF     (WTUPD_OFF + (size_t)128 * 256 * 2)   // bf16 [128][32] W3 transposed, K padded 16->32
#define REC_OFF     (W3T_OFF + (size_t)128 * 32 * 2)      // sorted 64B records = 40.96 MB
// record = 4 x uint4: [ ef bf16 x8 | ef bf16 x8 | {srcrow, dstrow, wgt, eid} | pad(unwritten) ]

static __device__ __forceinline__ unsigned short f2bf(float f) {
    __hip_bfloat16 h = __float2bfloat16(f);
    return *reinterpret_cast<unsigned short*>(&h);
}
static __device__ __forceinline__ float bfbits2f(unsigned bits16) {
    return __uint_as_float(bits16 << 16);
}

// GELU tanh-form via native rcp: g = x - x*rcp(e+1), e = exp(2z). ~7 VALU inst (validated r6).
static __device__ __forceinline__ float gelu_f(float x) {
    float x2 = x * x;
    float z2 = 1.5957691216f * x * __builtin_fmaf(0.044715f, x2, 1.0f);
    float e  = __expf(z2);
    float r  = __builtin_amdgcn_rcpf(e + 1.0f);
    return __builtin_fmaf(-x, r, x);
}

// dtype flag: gflag -> g_msg == ones. fp32 word0=0x3F800000 (low16==0); bf16 word0=0x3F803F80.
static __device__ __forceinline__ bool is_bf16_mode(const void* gflag) {
    return ((*reinterpret_cast<const unsigned*>(gflag)) & 0xFFFFu) != 0u;
}
static __device__ __forceinline__ float ld_f(const void* p, long i, bool bf) {
    return bf ? (float)reinterpret_cast<const __hip_bfloat16*>(p)[i]
              : reinterpret_cast<const float*>(p)[i];
}
static __device__ __forceinline__ uint4 pack8(const float* p) {
    float4 f0 = *reinterpret_cast<const float4*>(p);
    float4 f1 = *reinterpret_cast<const float4*>(p + 4);
    uint4 o;
    o.x = f2bf(f0.x) | ((unsigned)f2bf(f0.y) << 16);
    o.y = f2bf(f0.z) | ((unsigned)f2bf(f0.w) << 16);
    o.z = f2bf(f1.x) | ((unsigned)f2bf(f1.y) << 16);
    o.w = f2bf(f1.z) | ((unsigned)f2bf(f1.w) << 16);
    return o;
}
// 8 fp16 (uint4) -> 8 bf16 (uint4)
static __device__ __forceinline__ uint4 h8_to_bf8(uint4 u) {
    unsigned w[4] = {u.x, u.y, u.z, u.w};
    uint4 o; unsigned r[4];
    #pragma unroll
    for (int q = 0; q < 4; q++) {
        __half lo = *reinterpret_cast<const __half*>(&w[q]);
        unsigned short hib = (unsigned short)(w[q] >> 16);
        __half hi = *reinterpret_cast<const __half*>(&hib);
        r[q] = f2bf(__half2float(lo)) | ((unsigned)f2bf(__half2float(hi)) << 16);
    }
    o.x = r[0]; o.y = r[1]; o.z = r[2]; o.w = r[3];
    return o;
}
// component-wise wave shuffle of uint4
static __device__ __forceinline__ uint4 shfl4(uint4 v, int src) {
    uint4 o;
    o.x = (unsigned)__shfl((int)v.x, src);
    o.y = (unsigned)__shfl((int)v.y, src);
    o.z = (unsigned)__shfl((int)v.z, src);
    o.w = (unsigned)__shfl((int)v.w, src);
    return o;
}

// ---- fused init: zero agg (640000 uint4) + zero counts + weight prep ----
#define NCAT (256 * 128)
#define NUPD (128 * 256)
#define NW3  (128 * 32)
__global__ __launch_bounds__(256) void init_kernel(
    const void* __restrict__ Wmsg, const void* __restrict__ Wupd,
    const void* __restrict__ gflag,
    unsigned short* __restrict__ WtCat,
    unsigned short* __restrict__ WtUpd,
    unsigned short* __restrict__ W3t,
    uint4* __restrict__ aggz,
    uint4* __restrict__ cntz) {
    bool bf = is_bf16_mode(gflag);
    int i = blockIdx.x * 256 + threadIdx.x;    // grid = 2500*256 = 640000 exactly
    aggz[i] = make_uint4(0, 0, 0, 0);
    if (i < (int)(CNT_BYTES / 16)) cntz[i] = make_uint4(0, 0, 0, 0);
    if (i < NCAT) {
        int n = i >> 7, k = i & 127;
        int src = (n < 128) ? (k * 128 + n) : ((128 + k) * 128 + (n - 128));
        WtCat[i] = bf ? reinterpret_cast<const unsigned short*>(Wmsg)[src]
                      : f2bf(reinterpret_cast<const float*>(Wmsg)[src]);
    } else if (i < NCAT + NUPD) {
        int j = i - NCAT;
        int n = j >> 8, c = j & 255;
        WtUpd[j] = bf ? reinterpret_cast<const unsigned short*>(Wupd)[c * 128 + n]
                      : f2bf(reinterpret_cast<const float*>(Wupd)[c * 128 + n]);
    } else if (i < NCAT + NUPD + NW3) {
        int j = i - NCAT - NUPD;
        int n = j >> 5, k = j & 31;
        W3t[j] = (k < 16) ? (bf ? reinterpret_cast<const unsigned short*>(Wmsg)[(256 + k) * 128 + n]
                                : f2bf(reinterpret_cast<const float*>(Wmsg)[(256 + k) * 128 + n]))
                          : (unsigned short)0;
    }
}

// single-block exclusive scan over 40000 counts -> cursor. Wave-shuffle scan, reg-cached vals.
__global__ __launch_bounds__(1024) void scan_kernel(const int* __restrict__ counts,
                                                    int* __restrict__ cursor) {
    __shared__ int wsum[16];
    const int C = 40;                      // 1000 threads x 40 = 40000
    int tid = threadIdx.x, lane = tid & 63, wave = tid >> 6;
    int lo = tid * C;
    const bool act = (lo < NTOTN);
    int vals[C];
    int s = 0;
    if (act) {
        #pragma unroll
        for (int q = 0; q < C / 4; q++) {
            int4 t4 = *reinterpret_cast<const int4*>(counts + lo + q * 4);
            vals[q * 4 + 0] = t4.x; vals[q * 4 + 1] = t4.y;
            vals[q * 4 + 2] = t4.z; vals[q * 4 + 3] = t4.w;
            s += t4.x + t4.y + t4.z + t4.w;
        }
    }
    int sc = s;
    #pragma unroll
    for (int off = 1; off < 64; off <<= 1) {
        int v = __shfl_up(sc, off);
        if (lane >= off) sc += v;
    }
    if (lane == 63) wsum[wave] = sc;
    __syncthreads();
    if (wave == 0 && lane < 16) {
        int t = wsum[lane];
        #pragma unroll
        for (int off = 1; off < 16; off <<= 1) {
            int v = __shfl_up(t, off);
            if (lane >= off) t += v;
        }
        wsum[lane] = t;
    }
    __syncthreads();
    int run = (wave > 0 ? wsum[wave - 1] : 0) + (sc - s);
    if (act) {
        #pragma unroll
        for (int q = 0; q < C / 4; q++) {
            int4 o;
            o.x = run; run += vals[q * 4 + 0];
            o.y = run; run += vals[q * 4 + 1];
            o.z = run; run += vals[q * 4 + 2];
            o.w = run; run += vals[q * 4 + 3];
            *reinterpret_cast<int4*>(cursor + lo + q * 4) = o;
        }
    }
}

// scatter edges into dst-sorted 64B records; coalesced: groups of 4 lanes write one record's
// 3 meaningful words (48B contiguous) via shfl transpose. Pad word never written/read.
__global__ __launch_bounds__(256) void sort_scatter(
    const int*  __restrict__ edges,
    const void* __restrict__ ew,
    const void* __restrict__ ed,
    const void* __restrict__ efeat,
    const void* __restrict__ gflag,
    int*        __restrict__ cursor,
    uint4*      __restrict__ rec4)
{
    const bool bf = is_bf16_mode(gflag);
    int gid = blockIdx.x * 256 + threadIdx.x;   // grid exact: 2500*256 = NTOTE
    const int lane = threadIdx.x & 63, k = lane & 3, g4 = lane & ~3;
    int b = gid / NEDGES;
    long be = gid;
    int2 e = reinterpret_cast<const int2*>(edges)[gid];
    float w = ld_f(ew, be, bf) * ld_f(ed, be * 2 + 1, bf);
    uint4 R0, R1;
    if (bf) {
        const unsigned short* ep = reinterpret_cast<const unsigned short*>(efeat) + be * FEDIM;
        R0 = *reinterpret_cast<const uint4*>(ep);
        R1 = *reinterpret_cast<const uint4*>(ep + 8);
    } else {
        const float* ep = reinterpret_cast<const float*>(efeat) + be * FEDIM;
        R0 = pack8(ep);
        R1 = pack8(ep + 8);
    }
    uint4 R2 = make_uint4((unsigned)(b * NNODES + e.x),
                          (unsigned)(b * NNODES + e.y),
                          __float_as_uint(w),
                          (unsigned)gid);
    int pos = atomicAdd(&cursor[b * NNODES + e.y], 1);

    #pragma unroll
    for (int j = 0; j < 4; j++) {
        int src = g4 + j;
        uint4 a0 = shfl4(R0, src);
        uint4 a1 = shfl4(R1, src);
        uint4 a2 = shfl4(R2, src);
        int   pj = __shfl(pos, src);
        if (k < 3) {
            uint4 wv = (k == 0) ? a0 : (k == 1) ? a1 : a2;
            rec4[(size_t)pj * 4 + k] = wv;
        }
    }
}

// ---- precompute P = [nodes@W1 + b_msg | nodes@W2] (+ folded edge histogram) ----
__global__ __launch_bounds__(256) void pg_kernel(
    const void* __restrict__ nodes,
    const void* __restrict__ bmsg,
    const void* __restrict__ gflag,
    const unsigned short* __restrict__ Wt,    // [256][128]
    const int*  __restrict__ edges,
    int*        __restrict__ counts,
    unsigned short*       __restrict__ P)     // [B*N][256] permuted
{
    const bool bf = is_bf16_mode(gflag);
    __shared__ unsigned short sW[128 * 40];
    __shared__ unsigned short sA[128 * 40];

    const int tid  = threadIdx.x;
    const int lane = tid & 63, wave = tid >> 6;
    const int c    = lane & 15, quad = lane >> 4;
    const int row0 = blockIdx.x * 128;
    const int half = blockIdx.y;
    const int NROWS = BATCH * NNODES;

    // folded histogram: y==0 blocks cover all edges, 8 strided per thread (pre-barrier)
    if (half == 0) {
        #pragma unroll
        for (int k = 0; k < 8; k++) {
            int g = blockIdx.x * 2048 + k * 256 + tid;
            if (g < NTOTE) {
                int2 e = reinterpret_cast<const int2*>(edges)[g];
                atomicAdd(&counts[(g / NEDGES) * NNODES + e.y], 1);
            }
        }
    }

    float bcol[8];
    #pragma unroll
    for (int nt = 0; nt < 8; nt++)
        bcol[nt] = (half == 0) ? ld_f(bmsg, nt * 16 + c, bf) : 0.f;

    v4f acc[2][8];
    #pragma unroll
    for (int mt = 0; mt < 2; mt++)
        #pragma unroll
        for (int nt = 0; nt < 8; nt++) { v4f z = {0.f, 0.f, 0.f, 0.f}; acc[mt][nt] = z; }

    for (int ks = 0; ks < 4; ks++) {
        #pragma unroll
        for (int q = tid; q < 512; q += 256) {
            int n = q >> 2, part = q & 3;
            *reinterpret_cast<uint4*>(&sW[n * 40 + part * 8]) =
                *reinterpret_cast<const uint4*>(Wt + (half * 128 + n) * 128 + ks * 32 + part * 8);
        }
        #pragma unroll
        for (int q = tid; q < 512; q += 256) {
            int t = q >> 2, part = q & 3;
            int row = row0 + t; if (row >= NROWS) row = NROWS - 1;
            long off = (size_t)row * FDIM + ks * 32 + part * 8;
            uint4 v = bf ? *reinterpret_cast<const uint4*>(reinterpret_cast<const unsigned short*>(nodes) + off)
                         : pack8(reinterpret_cast<const float*>(nodes) + off);
            *reinterpret_cast<uint4*>(&sA[t * 40 + part * 8]) = v;
        }
        __syncthreads();

        v8s a0 = *reinterpret_cast<const v8s*>(&sA[(wave * 32 + c) * 40 + quad * 8]);
        v8s a1 = *reinterpret_cast<const v8s*>(&sA[(wave * 32 + 16 + c) * 40 + quad * 8]);
        #pragma unroll
        for (int nt = 0; nt < 8; nt++) {
            v8s bfr = *reinterpret_cast<const v8s*>(&sW[(nt * 16 + c) * 40 + quad * 8]);
            acc[0][nt] = __builtin_amdgcn_mfma_f32_16x16x32_bf16(a0, bfr, acc[0][nt], 0, 0, 0);
            acc[1][nt] = __builtin_amdgcn_mfma_f32_16x16x32_bf16(a1, bfr, acc[1][nt], 0, 0, 0);
        }
        __syncthreads();
    }

    #pragma unroll
    for (int mt = 0; mt < 2; mt++)
        #pragma unroll
        for (int r = 0; r < 4; r++) {
            int row = row0 + wave * 32 + mt * 16 + quad * 4 + r;
            if (row < NROWS) {
                float v[8];
                #pragma unroll
                for (int nt = 0; nt < 8; nt++) v[nt] = acc[mt][nt][r] + bcol[nt];
                uint4 o;
                o.x = f2bf(v[0]) | ((unsigned)f2bf(v[1]) << 16);
                o.y = f2bf(v[2]) | ((unsigned)f2bf(v[3]) << 16);
                o.z = f2bf(v[4]) | ((unsigned)f2bf(v[5]) << 16);
                o.w = f2bf(v[6]) | ((unsigned)f2bf(v[7]) << 16);
                *reinterpret_cast<uint4*>(P + (size_t)row * 256 + half * 128 + c * 8) = o;
            }
        }
}

// ---- per-edge (dst-SORTED, 64B recs): quad owns 32 contiguous sorted edges; 8 phases of
// {A-gather, 8 MFMA into acc[8], postprocess 4 edges} -> half the live accumulator regs of r6.
// Interior runs -> plain fp16x2 stores; chunk-straddling runs -> fp16x2 atomics.
__global__ __launch_bounds__(256) void edge_kernel(
    const unsigned short* __restrict__ P,     // [B*N][256] bf16, permuted rows
    const uint4*          __restrict__ rec4,  // 64B records
    const unsigned short* __restrict__ W3t,   // [128][32] bf16, K-padded
    const void* __restrict__ gmsg,            // gamma (and dtype flag)
    const void* __restrict__ betamsg,
    __half*     __restrict__ agg)             // [B*N][128] fp16
{
    const bool bf = is_bf16_mode(gmsg);
    const int tid  = threadIdx.x;
    const int lane = tid & 63, wave = tid >> 6;
    const int c    = lane & 15, quad = lane >> 4;
    const int wbase = blockIdx.x * 512 + wave * 128;  // wave's 128 sorted edges
    const int q0    = wbase + quad * 32;              // this quad's 32 sorted edges

    float gcol[8], becol[8];
    #pragma unroll
    for (int nt = 0; nt < 8; nt++) {
        gcol[nt]  = ld_f(gmsg, nt * 16 + c, bf);
        becol[nt] = ld_f(betamsg, nt * 16 + c, bf);
    }

    v8s bfrag[8];
    #pragma unroll
    for (int nt = 0; nt < 8; nt++)
        bfrag[nt] = *reinterpret_cast<const v8s*>(W3t + (nt * 16 + c) * 32 + quad * 8);

    // neighbor-chunk dst headers for straddle detection (quad-uniform loads)
    const int prevd = (q0 == 0) ? -1 : (int)rec4[(size_t)(q0 - 1) * 4 + 2].y;
    const int nextd = (q0 + 32 >= NTOTE) ? -1 : (int)rec4[(size_t)(q0 + 32) * 4 + 2].y;

    const bool even = !(c & 1);
    float racc[8];
    int  cur = -1;
    bool owned = true;   // current run started inside this chunk

    auto flushv = [&](int dstrow, bool plain) {
        __half* aout = agg + (size_t)dstrow * FDIM;
        #pragma unroll
        for (int np = 0; np < 4; np++) {
            int nt = np * 2;
            float t0 = __shfl_xor(racc[nt], 1);       // partner in-quad, same branch path
            float t1 = __shfl_xor(racc[nt + 1], 1);
            __half2 v = even ? __floats2half2_rn(racc[nt], t0)
                             : __floats2half2_rn(t1, racc[nt + 1]);
            int hoff = even ? (nt * 16 + c) : ((nt + 1) * 16 + c - 1);
            if (plain) *reinterpret_cast<__half2*>(aout + hoff) = v;
            else       unsafeAtomicAdd(reinterpret_cast<__half2*>(aout + hoff), v);
        }
    };

    #pragma unroll 1
    for (int ph = 0; ph < 8; ph++) {          // phase = (g, mt): 4 edges of this quad
        // A gather: lane's A-row c = quad (c>>2)'s edge ph*4 + (c&3)
        v8s a = {0, 0, 0, 0, 0, 0, 0, 0};
        if (quad < 2) {
            int slot = wbase + (c >> 2) * 32 + ph * 4 + (c & 3);
            uint4 u = rec4[(size_t)slot * 4 + quad];
            a = *reinterpret_cast<v8s*>(&u);
        }
        v4f acc[8];
        #pragma unroll
        for (int nt = 0; nt < 8; nt++) { v4f z = {0.f, 0.f, 0.f, 0.f}; acc[nt] = z; }
        #pragma unroll
        for (int nt = 0; nt < 8; nt++)
            acc[nt] = __builtin_amdgcn_mfma_f32_16x16x32_bf16(a, bfrag[nt], acc[nt], 0, 0, 0);

        uint4 H[4];
        #pragma unroll
        for (int r = 0; r < 4; r++)
            H[r] = rec4[(size_t)(q0 + ph * 4 + r) * 4 + 2];
        uint4 U1[4], U2[4];
        #pragma unroll
        for (int r = 0; r < 4; r++) {
            U1[r] = *reinterpret_cast<const uint4*>(P + (size_t)H[r].x * 256 + c * 8);
            U2[r] = *reinterpret_cast<const uint4*>(P + (size_t)H[r].y * 256 + 128 + c * 8);
        }
        #pragma unroll
        for (int r = 0; r < 4; r++) {
            unsigned w1[4] = {U1[r].x, U1[r].y, U1[r].z, U1[r].w};
            unsigned w2[4] = {U2[r].x, U2[r].y, U2[r].z, U2[r].w};
            float h[8];
            #pragma unroll
            for (int q = 0; q < 4; q++) {
                h[q * 2]     = bfbits2f(w1[q] & 0xFFFFu) + bfbits2f(w2[q] & 0xFFFFu) + acc[q * 2][r];
                h[q * 2 + 1] = __uint_as_float(w1[q] & 0xFFFF0000u) + __uint_as_float(w2[q] & 0xFFFF0000u)
                               + acc[q * 2 + 1][r];
            }
            float s = 0.f, sq = 0.f;
            #pragma unroll
            for (int nt = 0; nt < 8; nt++) {
                float gg = gelu_f(h[nt]);
                h[nt] = gg; s += gg; sq += gg * gg;
            }
            #pragma unroll
            for (int off = 1; off < 16; off <<= 1) {   // stays inside the quad
                s  += __shfl_xor(s, off);
                sq += __shfl_xor(sq, off);
            }
            float mu  = s * (1.0f / 128.0f);
            float var = sq * (1.0f / 128.0f) - mu * mu;
            float rs  = __builtin_amdgcn_rsqf(var + LNEPS);
            float wgt = __uint_as_float(H[r].z);
            int d = (int)H[r].y;
            if (d != cur) {               // quad-uniform branch
                if (cur >= 0) { flushv(cur, owned); owned = true; }
                else owned = (d != prevd);   // first run: extends left?
                cur = d;
                #pragma unroll
                for (int nt = 0; nt < 8; nt++)
                    racc[nt] = ((h[nt] - mu) * rs * gcol[nt] + becol[nt]) * wgt;
            } else {
                #pragma unroll
                for (int nt = 0; nt < 8; nt++)
                    racc[nt] += ((h[nt] - mu) * rs * gcol[nt] + becol[nt]) * wgt;
            }
        }
    }
    flushv(cur, owned && (cur != nextd));   // last run: plain iff starts AND ends inside
}

// ---- node update: [nodes | agg(fp16)] @ W_upd + b -> GELU -> LN -> out ----
__global__ __launch_bounds__(256) void upd_kernel(
    const void* __restrict__ nodes,
    const __half* __restrict__ agg,          // [B*N][128] fp16
    const unsigned short* __restrict__ Wt,   // [128][256]
    const void* __restrict__ bupd,
    const void* __restrict__ gupd,
    const void* __restrict__ beupd,
    void*       __restrict__ out)
{
    const bool bf = is_bf16_mode(gupd);
    __shared__ unsigned short sW[128 * 40];
    __shared__ unsigned short sA[64 * 40];

    const int tid  = threadIdx.x;
    const int lane = tid & 63, wave = tid >> 6;
    const int c    = lane & 15, quad = lane >> 4;
    const int row0 = blockIdx.x * 64;

    float bcol[8], gcol[8], becol[8];
    #pragma unroll
    for (int nt = 0; nt < 8; nt++) {
        int col = nt * 16 + c;
        bcol[nt]  = ld_f(bupd, col, bf);
        gcol[nt]  = ld_f(gupd, col, bf);
        becol[nt] = ld_f(beupd, col, bf);
    }

    v4f acc[8];
    #pragma unroll
    for (int nt = 0; nt < 8; nt++) { v4f z = {0.f, 0.f, 0.f, 0.f}; acc[nt] = z; }

    for (int ks = 0; ks < 8; ks++) {
        #pragma unroll
        for (int q = tid; q < 512; q += 256) {
            int n = q >> 2, part = q & 3;
            *reinterpret_cast<uint4*>(&sW[n * 40 + part * 8]) =
                *reinterpret_cast<const uint4*>(Wt + n * 256 + ks * 32 + part * 8);
        }
        {
            int t = tid >> 2, part = tid & 3;
            int row = row0 + t;
            uint4 v;
            if (ks < 4) {
                long off = (size_t)row * FDIM + ks * 32 + part * 8;
                v = bf ? *reinterpret_cast<const uint4*>(reinterpret_cast<const unsigned short*>(nodes) + off)
                       : pack8(reinterpret_cast<const float*>(nodes) + off);
            } else {
                uint4 u = *reinterpret_cast<const uint4*>(
                    reinterpret_cast<const unsigned short*>(agg) + (size_t)row * FDIM + (ks - 4) * 32 + part * 8);
                v = h8_to_bf8(u);
            }
            *reinterpret_cast<uint4*>(&sA[t * 40 + part * 8]) = v;
        }
        __syncthreads();

        v8s a0 = *reinterpret_cast<const v8s*>(&sA[(wave * 16 + c) * 40 + quad * 8]);
        #pragma unroll
        for (int nt = 0; nt < 8; nt++) {
            v8s bfr = *reinterpret_cast<const v8s*>(&sW[(nt * 16 + c) * 40 + quad * 8]);
            acc[nt] = __builtin_amdgcn_mfma_f32_16x16x32_bf16(a0, bfr, acc[nt], 0, 0, 0);
        }
        __syncthreads();
    }

    float s[4] = {0, 0, 0, 0}, sq[4] = {0, 0, 0, 0};
    #pragma unroll
    for (int nt = 0; nt < 8; nt++) {
        v4f v = acc[nt];
        #pragma unroll
        for (int r = 0; r < 4; r++) {
            float g = gelu_f(v[r] + bcol[nt]);
            v[r] = g;
            s[r] += g; sq[r] += g * g;
        }
        acc[nt] = v;
    }
    #pragma unroll
    for (int off = 1; off < 16; off <<= 1) {
        #pragma unroll
        for (int r = 0; r < 4; r++) {
            s[r]  += __shfl_xor(s[r], off);
            sq[r] += __shfl_xor(sq[r], off);
        }
    }
    #pragma unroll
    for (int r = 0; r < 4; r++) {
        float mu  = s[r] * (1.0f / 128.0f);
        float var = sq[r] * (1.0f / 128.0f) - mu * mu;
        float rs  = __builtin_amdgcn_rsqf(var + LNEPS);
        int row = row0 + wave * 16 + quad * 4 + r;
        #pragma unroll
        for (int nt = 0; nt < 8; nt++) {
            float y = (acc[nt][r] - mu) * rs * gcol[nt] + becol[nt];
            size_t oi = (size_t)row * FDIM + nt * 16 + c;
            if (bf) reinterpret_cast<__hip_bfloat16*>(out)[oi] = __float2bfloat16(y);
            else    reinterpret_cast<float*>(out)[oi] = y;
        }
    }
}

extern "C" void kernel_launch(void* const* d_in, const int* in_sizes, int n_in,
                              void* d_out, int out_size, void* d_ws, size_t ws_size,
                              hipStream_t stream)
{
    const void* nodes   = d_in[0];
    const void* efeat   = d_in[1];
    const int*  edges   = (const int*)d_in[2];
    const void* ew      = d_in[3];
    const void* ed      = d_in[4];
    const void* Wmsg    = d_in[5];
    const void* bmsg    = d_in[6];
    const void* gmsg    = d_in[7];   // ones -> dtype flag
    const void* betamsg = d_in[8];
    const void* Wupd    = d_in[9];
    const void* bupd    = d_in[10];
    const void* gupd    = d_in[11];
    const void* betaupd = d_in[12];

    char* ws = (char*)d_ws;
    __half* agg          = (__half*)ws;
    int*    counts       = (int*)(ws + CNT_OFF);
    int*    cursor       = (int*)(ws + CUR_OFF);
    unsigned short* P    = (unsigned short*)(ws + P_OFF);
    unsigned short* WtCat= (unsigned short*)(ws + WTCAT_OFF);
    unsigned short* WtUpd= (unsigned short*)(ws + WTUPD_OFF);
    unsigned short* W3t  = (unsigned short*)(ws + W3T_OFF);
    uint4*          rec4 = (uint4*)(ws + REC_OFF);

    // 6 dispatches: init(+zero agg/counts+prep), pg(+hist), scan, scatter, edge, upd
    init_kernel<<<2500, 256, 0, stream>>>(
        Wmsg, Wupd, gmsg, WtCat, WtUpd, W3t, (uint4*)agg, (uint4*)counts);
    pg_kernel<<<dim3(313, 2), 256, 0, stream>>>(
        nodes, bmsg, gmsg, WtCat, edges, counts, P);
    scan_kernel<<<1, 1024, 0, stream>>>(counts, cursor);
    sort_scatter<<<NTOTE / 256, 256, 0, stream>>>(
        edges, ew, ed, efeat, gmsg, cursor, rec4);
    edge_kernel<<<NTOTE / 512, 256, 0, stream>>>(
        P, rec4, W3t, gmsg, betamsg, agg);
    upd_kernel<<<NTOTN / 64, 256, 0, stream>>>(
        nodes, agg, WtUpd, bupd, gupd, betaupd, d_out);
}